// Round 1
// baseline (5609.939 us; speedup 1.0000x reference)
//
#include <hip/hip_runtime.h>
#include <hip/hip_bf16.h>

typedef __hip_bfloat16 bf16;
typedef float v4f __attribute__((ext_vector_type(4)));
typedef short v8s __attribute__((ext_vector_type(8)));

#define BB 4
#define TT 1024
#define DD 1024
#define HH 16
#define HD 64
#define LL 8
#define VV 50257
#define VP 50304   // V padded to multiple of 128
#define D3 3072
#define FF 4096

__device__ __forceinline__ void lds16(const void* g, void* l) {
    __builtin_amdgcn_global_load_lds(
        (const __attribute__((address_space(1))) void*)g,
        (__attribute__((address_space(3))) void*)l, 16, 0, 0);
}

__device__ __forceinline__ unsigned short bfbits(float f) {
    __hip_bfloat16 h = __float2bfloat16(f);
    return __builtin_bit_cast(unsigned short, h);
}

// ---------------- embedding: x = wte[idx] + wpe ----------------
__global__ void embed_kernel(const int* __restrict__ idx, const float* __restrict__ wte,
                             const float* __restrict__ wpe, float* __restrict__ x) {
    int bt = blockIdx.x, tid = threadIdx.x;
    int t = bt & (TT - 1);
    int tok = idx[bt];
    float4 w = ((const float4*)(wte + (size_t)tok * DD))[tid];
    float4 p = ((const float4*)(wpe + (size_t)t * DD))[tid];
    float4 r; r.x = w.x + p.x; r.y = w.y + p.y; r.z = w.z + p.z; r.w = w.w + p.w;
    ((float4*)(x + (size_t)bt * DD))[tid] = r;
}

// ---------------- weight convert+transpose f32[K,N] -> bf16[N,K] ----------------
__global__ void wconvT(const float* __restrict__ W, bf16* __restrict__ WT, int K, int N) {
    __shared__ float tile[32][33];
    size_t zoff = (size_t)blockIdx.z * K * N;
    int n0 = blockIdx.x * 32, k0 = blockIdx.y * 32;
    int tx = threadIdx.x, ty = threadIdx.y;
    const float* src = W + zoff;
    bf16* dst = WT + zoff;
#pragma unroll
    for (int i = 0; i < 4; i++)
        tile[ty + 8 * i][tx] = src[(size_t)(k0 + ty + 8 * i) * N + n0 + tx];
    __syncthreads();
#pragma unroll
    for (int i = 0; i < 4; i++)
        dst[(size_t)(n0 + ty + 8 * i) * K + k0 + tx] = __float2bfloat16(tile[tx][ty + 8 * i]);
}

// ---------------- wte f32[V,D] -> bf16[VP,D] (pad rows zeroed) ----------------
__global__ void wteconv(const float* __restrict__ wte, bf16* __restrict__ out) {
    int row = blockIdx.x, tid = threadIdx.x;
    ushort4 o4;
    if (row < VV) {
        float4 v = ((const float4*)(wte + (size_t)row * DD))[tid];
        o4.x = bfbits(v.x); o4.y = bfbits(v.y); o4.z = bfbits(v.z); o4.w = bfbits(v.w);
    } else {
        o4.x = 0; o4.y = 0; o4.z = 0; o4.w = 0;
    }
    *(ushort4*)((unsigned short*)out + (size_t)row * DD + tid * 4) = o4;
}

// ---------------- layernorm f32 -> bf16 ----------------
__global__ void ln_kernel(const float* __restrict__ x, const float* __restrict__ g,
                          const float* __restrict__ bta, bf16* __restrict__ out) {
    int row = blockIdx.x, tid = threadIdx.x;
    float4 v = ((const float4*)(x + (size_t)row * DD))[tid];
    float s1 = v.x + v.y + v.z + v.w;
    float s2 = v.x * v.x + v.y * v.y + v.z * v.z + v.w * v.w;
#pragma unroll
    for (int off = 32; off; off >>= 1) { s1 += __shfl_xor(s1, off); s2 += __shfl_xor(s2, off); }
    __shared__ float red[8];
    int wave = tid >> 6, lane = tid & 63;
    if (lane == 0) { red[wave] = s1; red[4 + wave] = s2; }
    __syncthreads();
    s1 = red[0] + red[1] + red[2] + red[3];
    s2 = red[4] + red[5] + red[6] + red[7];
    float mu = s1 * (1.0f / DD);
    float var = s2 * (1.0f / DD) - mu * mu;
    float rstd = rsqrtf(var + 1e-5f);
    float4 gg = ((const float4*)g)[tid];
    float4 bb = ((const float4*)bta)[tid];
    ushort4 o4;
    o4.x = bfbits((v.x - mu) * rstd * gg.x + bb.x);
    o4.y = bfbits((v.y - mu) * rstd * gg.y + bb.y);
    o4.z = bfbits((v.z - mu) * rstd * gg.z + bb.z);
    o4.w = bfbits((v.w - mu) * rstd * gg.w + bb.w);
    *(ushort4*)((unsigned short*)out + (size_t)row * DD + tid * 4) = o4;
}

// ---------------- causal softmax (in-place: f32 S row -> bf16 P row) ----------------
__global__ void softmax_causal(float* __restrict__ S) {
    int q = blockIdx.x, hh = blockIdx.y, tid = threadIdx.x;
    float* srow = S + ((size_t)hh * TT + q) * TT;
    float4 v = ((const float4*)srow)[tid];
    int j0 = tid * 4;
    float vv[4] = {v.x, v.y, v.z, v.w};
    float m = -3.0e38f;
#pragma unroll
    for (int e = 0; e < 4; e++) if (j0 + e <= q) m = fmaxf(m, vv[e]);
#pragma unroll
    for (int off = 32; off; off >>= 1) m = fmaxf(m, __shfl_xor(m, off));
    __shared__ float red[4];
    int wave = tid >> 6, lane = tid & 63;
    if (lane == 0) red[wave] = m;
    __syncthreads();
    m = fmaxf(fmaxf(red[0], red[1]), fmaxf(red[2], red[3]));
    __syncthreads();
    float ex[4]; float s = 0.f;
#pragma unroll
    for (int e = 0; e < 4; e++) { ex[e] = (j0 + e <= q) ? __expf(vv[e] - m) : 0.0f; s += ex[e]; }
#pragma unroll
    for (int off = 32; off; off >>= 1) s += __shfl_xor(s, off);
    if (lane == 0) red[wave] = s;
    __syncthreads();
    s = red[0] + red[1] + red[2] + red[3];
    float inv = 1.0f / s;
    ushort4 o4;
    o4.x = bfbits(ex[0] * inv); o4.y = bfbits(ex[1] * inv);
    o4.z = bfbits(ex[2] * inv); o4.w = bfbits(ex[3] * inv);
    *(ushort4*)((unsigned short*)srow + j0) = o4;  // P row, pitch 2048 bf16 elems
}

// ---------------- V transpose per batch: qkv v-section -> Vt[h][64][1024] ----------------
__global__ void vtrans(const bf16* __restrict__ qkvb, bf16* __restrict__ Vt) {
    __shared__ bf16 tile[32][33];
    int k0 = blockIdx.x * 32, n0 = blockIdx.y * 32, hh = blockIdx.z;
    int tx = threadIdx.x, ty = threadIdx.y;
    const bf16* src = qkvb + 2 * DD + hh * HD;
#pragma unroll
    for (int i = 0; i < 4; i++)
        tile[ty + 8 * i][tx] = src[(size_t)(k0 + ty + 8 * i) * D3 + n0 + tx];
    __syncthreads();
    bf16* dst = Vt + (size_t)hh * HD * TT;
#pragma unroll
    for (int i = 0; i < 4; i++)
        dst[(size_t)(n0 + ty + 8 * i) * TT + k0 + tx] = tile[tx][ty + 8 * i];
}

// ---------------- generic NT GEMM: C[m,n] = sum_k A[m,k]*B[n,k] ----------------
// EPI: 0 = bf16 store; 1 = f32 residual (+optional bias); 2 = bias+GELU -> bf16;
//      3 = f32 store; 4 = scale + causal mask -> f32
template <int EPI>
__launch_bounds__(256, 2)
__global__ void gemm_nt(const bf16* __restrict__ A, int lda, long long sAz,
                        const bf16* __restrict__ B, int ldb, long long sBz, int Nb,
                        void* __restrict__ C, int ldc, long long sCz, int Nstore,
                        int K, const float* __restrict__ bias, float scale) {
    int m0 = blockIdx.x * 128, n0 = blockIdx.y * 128;
    if (EPI == 4 && n0 > m0 + 127) return;   // fully-masked causal block
    A += (size_t)blockIdx.z * sAz;
    B += (size_t)blockIdx.z * sBz;
    size_t czoff = (size_t)blockIdx.z * sCz;

    __shared__ short As[128 * 32];
    __shared__ short Bs[128 * 32];
    int tid = threadIdx.x;
    int lane = tid & 63, wave = tid >> 6;
    int wm = (wave & 1) * 64, wn = (wave >> 1) * 64;
    int mrow = lane & 15, quad = lane >> 4;

    v4f zero = {0.f, 0.f, 0.f, 0.f};
    v4f acc[4][4];
#pragma unroll
    for (int i = 0; i < 4; i++)
#pragma unroll
        for (int j = 0; j < 4; j++) acc[i][j] = zero;

    int c0 = tid, c1 = tid + 256;
    int rA0 = c0 >> 2, kA0 = (c0 & 3) * 8;
    int rA1 = c1 >> 2, kA1 = (c1 & 3) * 8;
    int br0 = n0 + rA0; if (br0 >= Nb) br0 = Nb - 1;
    int br1 = n0 + rA1; if (br1 >= Nb) br1 = Nb - 1;

    for (int k0 = 0; k0 < K; k0 += 32) {
        lds16(A + (size_t)(m0 + rA0) * lda + k0 + kA0, &As[c0 * 8]);
        lds16(A + (size_t)(m0 + rA1) * lda + k0 + kA1, &As[c1 * 8]);
        lds16(B + (size_t)br0 * ldb + k0 + kA0, &Bs[c0 * 8]);
        lds16(B + (size_t)br1 * ldb + k0 + kA1, &Bs[c1 * 8]);
        __syncthreads();
        v8s af[4], bfr[4];
#pragma unroll
        for (int i = 0; i < 4; i++)
            af[i] = *(const v8s*)&As[(wm + i * 16 + mrow) * 32 + quad * 8];
#pragma unroll
        for (int i = 0; i < 4; i++)
            bfr[i] = *(const v8s*)&Bs[(wn + i * 16 + mrow) * 32 + quad * 8];
#pragma unroll
        for (int mi = 0; mi < 4; mi++)
#pragma unroll
            for (int ni = 0; ni < 4; ni++)
                acc[mi][ni] = __builtin_amdgcn_mfma_f32_16x16x32_bf16(
                    af[mi], bfr[ni], acc[mi][ni], 0, 0, 0);
        __syncthreads();
    }

#pragma unroll
    for (int ni = 0; ni < 4; ni++) {
        int col = n0 + wn + ni * 16 + mrow;
        if (col >= Nstore) continue;
        float bv = (EPI == 1 || EPI == 2) ? (bias ? bias[col] : 0.f) : 0.f;
#pragma unroll
        for (int mi = 0; mi < 4; mi++) {
#pragma unroll
            for (int r = 0; r < 4; r++) {
                int row = m0 + wm + mi * 16 + quad * 4 + r;
                float v = acc[mi][ni][r];
                size_t off = czoff + (size_t)row * ldc + col;
                if (EPI == 0) {
                    ((bf16*)C)[off] = __float2bfloat16(v);
                } else if (EPI == 1) {
                    ((float*)C)[off] += v + bv;
                } else if (EPI == 2) {
                    float t = v + bv;
                    float ge = 0.5f * t * (1.0f + erff(t * 0.70710678118f));
                    ((bf16*)C)[off] = __float2bfloat16(ge);
                } else if (EPI == 3) {
                    ((float*)C)[off] = v;
                } else {
                    float sc = v * scale;
                    if (col > row) sc = -1e30f;
                    ((float*)C)[off] = sc;
                }
            }
        }
    }
}

extern "C" void kernel_launch(void* const* d_in, const int* in_sizes, int n_in,
                              void* d_out, int out_size, void* d_ws, size_t ws_size,
                              hipStream_t stream) {
    const int*   idx    = (const int*)d_in[0];
    const float* wte    = (const float*)d_in[1];
    const float* wpe    = (const float*)d_in[2];
    const float* ln1_g  = (const float*)d_in[3];
    const float* ln1_b  = (const float*)d_in[4];
    const float* ln2_g  = (const float*)d_in[5];
    const float* ln2_b  = (const float*)d_in[6];
    const float* qkv_w  = (const float*)d_in[7];
    const float* proj_w = (const float*)d_in[8];
    const float* ff1_w  = (const float*)d_in[9];
    const float* ff1_b  = (const float*)d_in[10];
    const float* ff2_w  = (const float*)d_in[11];
    const float* ff2_b  = (const float*)d_in[12];
    const float* lnf_g  = (const float*)d_in[13];
    const float* lnf_b  = (const float*)d_in[14];
    float* out = (float*)d_out;

    // ---- workspace carve (~466 MB total) ----
    char* p = (char*)d_ws;
    auto carve = [&](size_t bytes) { char* r = p; p += (bytes + 255) & ~(size_t)255; return r; };
    bf16*  wteb   = (bf16*)carve((size_t)VP * DD * 2);
    bf16*  qkvwT  = (bf16*)carve((size_t)LL * DD * D3 * 2);
    bf16*  projwT = (bf16*)carve((size_t)LL * DD * DD * 2);
    bf16*  ff1wT  = (bf16*)carve((size_t)LL * DD * FF * 2);
    bf16*  ff2wT  = (bf16*)carve((size_t)LL * FF * DD * 2);
    float* x      = (float*)carve((size_t)BB * TT * DD * 4);
    bf16*  h      = (bf16*)carve((size_t)BB * TT * DD * 2);
    bf16*  qkv    = (bf16*)carve((size_t)BB * TT * D3 * 2);
    float* Sbuf   = (float*)carve((size_t)HH * TT * TT * 4);   // per-batch, reused
    bf16*  Vt     = (bf16*)carve((size_t)HH * HD * TT * 2);    // per-batch, reused
    bf16*  o      = (bf16*)carve((size_t)BB * TT * DD * 2);
    bf16*  ffb    = (bf16*)carve((size_t)BB * TT * FF * 2);

    dim3 t256(256), t328(32, 8);

    // weights -> bf16 (transposed to [N,K]); wte -> bf16 padded
    wteconv<<<dim3(VP), t256, 0, stream>>>(wte, wteb);
    wconvT<<<dim3(D3 / 32, DD / 32, LL), t328, 0, stream>>>(qkv_w, qkvwT, DD, D3);
    wconvT<<<dim3(DD / 32, DD / 32, LL), t328, 0, stream>>>(proj_w, projwT, DD, DD);
    wconvT<<<dim3(FF / 32, DD / 32, LL), t328, 0, stream>>>(ff1_w, ff1wT, DD, FF);
    wconvT<<<dim3(DD / 32, FF / 32, LL), t328, 0, stream>>>(ff2_w, ff2wT, FF, DD);

    embed_kernel<<<dim3(BB * TT), t256, 0, stream>>>(idx, wte, wpe, x);

    for (int l = 0; l < LL; l++) {
        // NOTE reference quirk: ln2 params before attention, ln1 before FFN
        ln_kernel<<<dim3(BB * TT), t256, 0, stream>>>(x, ln2_g + l * DD, ln2_b + l * DD, h);
        gemm_nt<0><<<dim3(32, 24), t256, 0, stream>>>(
            h, DD, 0, qkvwT + (size_t)l * DD * D3, DD, 0, D3,
            qkv, D3, 0, D3, DD, nullptr, 1.f);

        for (int b = 0; b < BB; b++) {
            const bf16* qkvb = qkv + (size_t)b * TT * D3;
            vtrans<<<dim3(TT / 32, 2, HH), t328, 0, stream>>>(qkvb, Vt);
            // S = scale * Q K^T  (causal)
            gemm_nt<4><<<dim3(8, 8, HH), t256, 0, stream>>>(
                qkvb, D3, HD, qkvb + DD, D3, HD, TT,
                Sbuf, TT, (long long)TT * TT, TT, HD, nullptr, 0.125f);
            softmax_causal<<<dim3(TT, HH), t256, 0, stream>>>(Sbuf);
            // O = P V   (P = bf16 rows in-place over S, pitch 2048 elems)
            gemm_nt<0><<<dim3(8, 1, HH), t256, 0, stream>>>(
                (const bf16*)Sbuf, 2048, (long long)TT * 2048,
                Vt, TT, (long long)HD * TT, HD,
                o + (size_t)b * TT * DD, DD, HD, HD, TT, nullptr, 1.f);
        }
        // x += o @ proj
        gemm_nt<1><<<dim3(32, 8), t256, 0, stream>>>(
            o, DD, 0, projwT + (size_t)l * DD * DD, DD, 0, DD,
            x, DD, 0, DD, DD, nullptr, 1.f);
        // FFN
        ln_kernel<<<dim3(BB * TT), t256, 0, stream>>>(x, ln1_g + l * DD, ln1_b + l * DD, h);
        gemm_nt<2><<<dim3(32, 32), t256, 0, stream>>>(
            h, DD, 0, ff1wT + (size_t)l * DD * FF, DD, 0, FF,
            ffb, FF, 0, FF, DD, ff1_b + l * FF, 1.f);
        gemm_nt<1><<<dim3(32, 8), t256, 0, stream>>>(
            ffb, FF, 0, ff2wT + (size_t)l * FF * DD, FF, 0, DD,
            x, DD, 0, DD, FF, ff2_b + l * DD, 1.f);
    }

    ln_kernel<<<dim3(BB * TT), t256, 0, stream>>>(x, lnf_g, lnf_b, h);
    // logits = h @ wte^T
    gemm_nt<3><<<dim3(32, VP / 128), t256, 0, stream>>>(
        h, DD, 0, wteb, DD, 0, VP,
        out, VV, 0, VV, DD, nullptr, 1.f);
}